// Round 7
// baseline (279.866 us; speedup 1.0000x reference)
//
#include <hip/hip_runtime.h>
#include <hip/hip_bf16.h>

// BERT self-attention, B=4 S=2048 H=16 Dh=64, fp32 in/out, bf16 MFMA compute.
// Round 7: attn refinements on the verified round-6 structure:
//   (1) KVBLK=128 (half the barriers; PV folded per-kb so regs stay flat)
//   (2) shfl-halving: 1 shfl_xor + 3 selects per word-pair (was 2+2),
//       derivation enumerated equivalent to the verified select tables
//   (3) s_setprio(1) around MFMA clusters (T5)
// GEMMs/convs identical to round 6 (verified).

typedef float  f32x4  __attribute__((ext_vector_type(4)));
typedef float  f32x16 __attribute__((ext_vector_type(16)));
typedef short  short8 __attribute__((ext_vector_type(8)));
typedef __bf16 bf16x8 __attribute__((ext_vector_type(8)));
typedef unsigned int uint4v __attribute__((ext_vector_type(4)));

#define AS1 __attribute__((address_space(1)))
#define AS3 __attribute__((address_space(3)))

__device__ __forceinline__ void gload_lds16(const void* g, void* l) {
    __builtin_amdgcn_global_load_lds((const AS1 void*)g, (AS3 void*)l, 16, 0, 0);
}

__device__ __forceinline__ unsigned short f2bf(float f) {
    union { float f; unsigned int u; } v; v.f = f;
    unsigned int u = v.u;
    unsigned int r = (u + 0x7fffu + ((u >> 16) & 1u)) >> 16;   // RTNE
    return (unsigned short)r;
}

__device__ __forceinline__ unsigned packbf(float a, float b) {
    unsigned short lo = __builtin_bit_cast(unsigned short, (__bf16)a);
    unsigned short hh = __builtin_bit_cast(unsigned short, (__bf16)b);
    return (unsigned)lo | ((unsigned)hh << 16);
}

__device__ __forceinline__ f32x4 mfma16(short8 a, short8 b, f32x4 c) {
    return __builtin_amdgcn_mfma_f32_16x16x32_bf16(
        __builtin_bit_cast(bf16x8, a), __builtin_bit_cast(bf16x8, b), c, 0, 0, 0);
}

__device__ __forceinline__ f32x16 mfma32(short8 a, short8 b, f32x16 c) {
    return __builtin_amdgcn_mfma_f32_32x32x16_bf16(
        __builtin_bit_cast(bf16x8, a), __builtin_bit_cast(bf16x8, b), c, 0, 0, 0);
}

__device__ __forceinline__ f32x16 mfma32u(uint4v a, short8 b, f32x16 c) {
    return __builtin_amdgcn_mfma_f32_32x32x16_bf16(
        __builtin_bit_cast(bf16x8, a), __builtin_bit_cast(bf16x8, b), c, 0, 0, 0);
}

// ---------------- conversion kernels ----------------

__global__ void conv_x(const float* __restrict__ X, unsigned short* __restrict__ Xb, int n4) {
    int i = blockIdx.x * blockDim.x + threadIdx.x;
    int stride = gridDim.x * blockDim.x;
    for (; i < n4; i += stride) {
        float4 v = ((const float4*)X)[i];
        ushort4 o;
        o.x = f2bf(v.x); o.y = f2bf(v.y); o.z = f2bf(v.z); o.w = f2bf(v.w);
        ((ushort4*)Xb)[i] = o;
    }
}

__global__ void conv_w_t(const float* __restrict__ Wq, const float* __restrict__ Wk,
                         const float* __restrict__ Wv,
                         unsigned short* __restrict__ Wqt, unsigned short* __restrict__ Wkt,
                         unsigned short* __restrict__ Wvt) {
    const float* W = (blockIdx.z == 0) ? Wq : (blockIdx.z == 1) ? Wk : Wv;
    unsigned short* Wt = (blockIdx.z == 0) ? Wqt : (blockIdx.z == 1) ? Wkt : Wvt;
    __shared__ unsigned short tile[64][65];
    int n0 = blockIdx.x * 64, k0 = blockIdx.y * 64;
    int t = threadIdx.x;
    int cr = t >> 6, cc = t & 63;
    for (int i = 0; i < 16; i++) {
        int row = i * 4 + cr;
        tile[row][cc] = f2bf(W[(size_t)(k0 + row) * 1024 + n0 + cc]);
    }
    __syncthreads();
    for (int i = 0; i < 16; i++) {
        int row = i * 4 + cr;
        Wt[(size_t)(n0 + row) * 1024 + k0 + cc] = tile[cc][row];
    }
}

// ---------------- GEMM: Q & K fused (z), double-buffered 2-phase ----------------

__global__ __launch_bounds__(256)
void gemm_qk(const unsigned short* __restrict__ A,
             const unsigned short* __restrict__ Bt0, const unsigned short* __restrict__ Bt1,
             const float* __restrict__ bias0, const float* __restrict__ bias1,
             unsigned short* __restrict__ o0, unsigned short* __restrict__ o1) {
    __shared__ unsigned short Alds[2][4096];
    __shared__ unsigned short Blds[2][4096];
    const int K = 1024;
    const int z = blockIdx.z;
    const unsigned short* Bt = z ? Bt1 : Bt0;
    const float* bias = z ? bias1 : bias0;
    unsigned short* out = z ? o1 : o0;
    const float scale = z ? 1.0f : 0.125f;

    int t = threadIdx.x;
    int m0 = blockIdx.y * 128, n0 = blockIdx.x * 128;
    int wid = t >> 6, lane = t & 63, g = lane >> 4, r16 = lane & 15;
    int wr = wid >> 1, wc = wid & 1;

    f32x4 acc[4][4] = {};

    const unsigned short* Ab = A + (size_t)(m0 + (t >> 2)) * K + (t & 3) * 8;
    const unsigned short* Bb = Bt + (size_t)(n0 + (t >> 2)) * K + (t & 3) * 8;

#define STAGE_G(buf, k0)                                              \
    gload_lds16(Ab + (k0), &Alds[buf][wid * 512]);                    \
    gload_lds16(Ab + (k0) + (size_t)64 * K, &Alds[buf][2048 + wid * 512]); \
    gload_lds16(Bb + (k0), &Blds[buf][wid * 512]);                    \
    gload_lds16(Bb + (k0) + (size_t)64 * K, &Blds[buf][2048 + wid * 512]);

    STAGE_G(0, 0)
    asm volatile("s_waitcnt vmcnt(0)" ::: "memory");
    __syncthreads();

    int cur = 0;
    for (int k0 = 0; k0 < K; k0 += 32) {
        if (k0 + 32 < K) { STAGE_G(cur ^ 1, k0 + 32) }
        short8 af[4], bfr[4];
        #pragma unroll
        for (int m = 0; m < 4; m++)
            af[m] = *(const short8*)&Alds[cur][(wr * 64 + m * 16 + r16) * 32 + g * 8];
        #pragma unroll
        for (int n = 0; n < 4; n++)
            bfr[n] = *(const short8*)&Blds[cur][(wc * 64 + n * 16 + r16) * 32 + g * 8];
        #pragma unroll
        for (int m = 0; m < 4; m++)
            #pragma unroll
            for (int n = 0; n < 4; n++)
                acc[m][n] = mfma16(af[m], bfr[n], acc[m][n]);
        asm volatile("s_waitcnt vmcnt(0)" ::: "memory");
        __syncthreads();
        cur ^= 1;
    }

    for (int m = 0; m < 4; m++) {
        int gmBase = m0 + wr * 64 + m * 16 + g * 4;
        for (int n = 0; n < 4; n++) {
            int gn = n0 + wc * 64 + n * 16 + r16;
            float bcol = bias[gn];
            for (int r = 0; r < 4; r++) {
                int gm = gmBase + r;
                float v = (acc[m][n][r] + bcol) * scale;
                int b = gm >> 11, s = gm & 2047, h = gn >> 6, d = gn & 63;
                out[((size_t)(b * 16 + h) * 2048 + s) * 64 + d] = f2bf(v);
            }
        }
    }
}

// ---------------- GEMM: Vt = Wvt x Xb^T (M=1024, N=8192), double-buffered ----

__global__ __launch_bounds__(256)
void gemm_v(const unsigned short* __restrict__ A, const unsigned short* __restrict__ Bt,
            const float* __restrict__ bias, unsigned short* __restrict__ out) {
    __shared__ unsigned short Alds[2][4096];
    __shared__ unsigned short Blds[2][4096];
    const int K = 1024, N = 8192;

    int t = threadIdx.x;
    int m0 = blockIdx.y * 128, n0 = blockIdx.x * 128;
    int wid = t >> 6, lane = t & 63, g = lane >> 4, r16 = lane & 15;
    int wr = wid >> 1, wc = wid & 1;

    f32x4 acc[4][4] = {};

    const unsigned short* Ab = A + (size_t)(m0 + (t >> 2)) * K + (t & 3) * 8;
    const unsigned short* Bb = Bt + (size_t)(n0 + (t >> 2)) * K + (t & 3) * 8;

    STAGE_G(0, 0)
    asm volatile("s_waitcnt vmcnt(0)" ::: "memory");
    __syncthreads();

    int cur = 0;
    for (int k0 = 0; k0 < K; k0 += 32) {
        if (k0 + 32 < K) { STAGE_G(cur ^ 1, k0 + 32) }
        short8 af[4], bfr[4];
        #pragma unroll
        for (int m = 0; m < 4; m++)
            af[m] = *(const short8*)&Alds[cur][(wr * 64 + m * 16 + r16) * 32 + g * 8];
        #pragma unroll
        for (int n = 0; n < 4; n++)
            bfr[n] = *(const short8*)&Blds[cur][(wc * 64 + n * 16 + r16) * 32 + g * 8];
        #pragma unroll
        for (int m = 0; m < 4; m++)
            #pragma unroll
            for (int n = 0; n < 4; n++)
                acc[m][n] = mfma16(af[m], bfr[n], acc[m][n]);
        asm volatile("s_waitcnt vmcnt(0)" ::: "memory");
        __syncthreads();
        cur ^= 1;
    }

    for (int m = 0; m < 4; m++) {
        int gmBase = m0 + wr * 64 + m * 16 + g * 4;
        for (int n = 0; n < 4; n++) {
            int gn = n0 + wc * 64 + n * 16 + r16;
            for (int r = 0; r < 4; r++) {
                int gm = gmBase + r;
                out[(size_t)gm * N + gn] = f2bf(acc[m][n][r] + bias[gm]);
            }
        }
    }
}

// ---------------- flash attention, 32x32 swapped, KVBLK=128 ----------------
// Q,K: [B*H][S][64] bf16 (Q pre-scaled by 0.125); Vt: [1024][8192] bf16;
// mask: [B][S] f32 raw; out: [B][S][1024] f32.
// 256 thr = 4 waves; wave owns 64 q-rows. KV tile 128 (dbuf, 16 barriers).
// K LDS [128][64] chunk-XOR swizzled; V LDS [64][128] chunk-XOR swizzled
// (low 3 bits of 4-bit chunk index). Staging pre-swizzles the GLOBAL source.
// QK^T swapped: St[t][q] = mfma32(K-frag, Q-frag), C-init = mask[t].
// C layout: col q = lane&31, row t = (reg&3)+8*(reg>>2)+4*hi.
// P->PV A-frags via pack + 1 shfl_xor(.,32) + 3 selects per word-pair.

__global__ __launch_bounds__(256, 2)
void attn(const unsigned short* __restrict__ Qb, const unsigned short* __restrict__ Kb,
          const unsigned short* __restrict__ Vtb, const float* __restrict__ mask,
          float* __restrict__ out) {
    __shared__ unsigned short Kl[2][8192];
    __shared__ unsigned short Vl[2][8192];
    __shared__ float sums[4][64];

    const int t = threadIdx.x, wid = t >> 6, lane = t & 63;
    const int hi = lane >> 5, c = lane & 31;
    const int bh = blockIdx.x, b = bh >> 4, h = bh & 15;
    const int q0w = blockIdx.y * 256 + wid * 64;

    // Q fragments (B-operand): lane holds Q[q0w+qh*32+c][ds*16+hi*8 .. +7]
    short8 qf[2][4];
    #pragma unroll
    for (int qh = 0; qh < 2; qh++)
        #pragma unroll
        for (int ds = 0; ds < 4; ds++)
            qf[qh][ds] = *(const short8*)&Qb[((size_t)bh * 2048 + q0w + qh * 32 + c) * 64
                                             + ds * 16 + hi * 8];

    float lsum[2] = {0.f, 0.f};
    f32x16 ctx[2][2] = {};   // [qh][dblk]

    // K staging: instr i covers rows i*32 + (t>>3); chunk ^= row&7
    const int srow = t >> 3;
    const int schk = (t & 7) ^ (srow & 7);
    const unsigned short* Kst = Kb + (size_t)bh * 2048 * 64 + srow * 64 + schk * 8;
    // V staging: instr i covers rows i*16 + (t>>4); 4-bit chunk, XOR low 3 bits
    const int vd = t >> 4;
    const int vchk = (t & 15) ^ (vd & 7);
    const unsigned short* Vst = Vtb + (size_t)(h * 64 + vd) * 8192 + (size_t)b * 2048 + vchk * 8;
    const float* mrow = mask + (size_t)b * 2048;

#define STAGE_KV(buf, T0)                                                         \
    gload_lds16(Kst + (size_t)(T0) * 64,         &Kl[buf][wid * 512]);            \
    gload_lds16(Kst + (size_t)((T0) + 32) * 64,  &Kl[buf][2048 + wid * 512]);     \
    gload_lds16(Kst + (size_t)((T0) + 64) * 64,  &Kl[buf][4096 + wid * 512]);     \
    gload_lds16(Kst + (size_t)((T0) + 96) * 64,  &Kl[buf][6144 + wid * 512]);     \
    gload_lds16(Vst + (T0),                      &Vl[buf][wid * 512]);            \
    gload_lds16(Vst + (T0) + (size_t)16 * 8192,  &Vl[buf][2048 + wid * 512]);     \
    gload_lds16(Vst + (T0) + (size_t)32 * 8192,  &Vl[buf][4096 + wid * 512]);     \
    gload_lds16(Vst + (T0) + (size_t)48 * 8192,  &Vl[buf][6144 + wid * 512]);

    STAGE_KV(0, 0)
    asm volatile("s_waitcnt vmcnt(0)" ::: "memory");
    __syncthreads();

    int cur = 0;
    for (int t0 = 0; t0 < 2048; t0 += 128) {
        if (t0 + 128 < 2048) { STAGE_KV(cur ^ 1, t0 + 128) }
        const unsigned short* K_ = Kl[cur];
        const unsigned short* V_ = Vl[cur];

        #pragma unroll
        for (int kb = 0; kb < 4; kb++) {
            const int krow = kb * 32 + c;
            short8 kf[4];
            #pragma unroll
            for (int ds = 0; ds < 4; ds++)
                kf[ds] = *(const short8*)&K_[krow * 64 + (((ds * 2 + hi) ^ (krow & 7)) * 8)];
            float4 m4[4];
            #pragma unroll
            for (int q = 0; q < 4; q++)
                m4[q] = *(const float4*)&mrow[t0 + kb * 32 + q * 8 + hi * 4];

            uint4v pa[2][2];   // [qh][local t-chunk]
            #pragma unroll
            for (int qh = 0; qh < 2; qh++) {
                f32x16 st;
                #pragma unroll
                for (int q = 0; q < 4; q++) {
                    st[q * 4 + 0] = m4[q].x; st[q * 4 + 1] = m4[q].y;
                    st[q * 4 + 2] = m4[q].z; st[q * 4 + 3] = m4[q].w;
                }
                __builtin_amdgcn_s_setprio(1);
                #pragma unroll
                for (int ds = 0; ds < 4; ds++)
                    st = mfma32(kf[ds], qf[qh][ds], st);
                __builtin_amdgcn_s_setprio(0);
                float p[16];
                #pragma unroll
                for (int r = 0; r < 16; r++) {
                    p[r] = __expf(st[r]);
                    lsum[qh] += p[r];
                }
                unsigned cc[8];
                #pragma unroll
                for (int i = 0; i < 8; i++) cc[i] = packbf(p[2 * i], p[2 * i + 1]);
                // word-pair mix: 1 shfl + 3 selects, equivalent to the verified
                // {hi?sx[i+2]:cc[i], hi?cc[i+2]:sx[i]} tables
                unsigned w[8];
                #pragma unroll
                for (int i = 0; i < 2; i++) {
                    {
                        unsigned u = hi ? cc[i] : cc[i + 2];
                        unsigned s = __shfl_xor(u, 32);
                        w[i]     = hi ? s : cc[i];
                        w[i + 2] = hi ? cc[i + 2] : s;
                    }
                    {
                        unsigned u = hi ? cc[i + 4] : cc[i + 6];
                        unsigned s = __shfl_xor(u, 32);
                        w[i + 4] = hi ? s : cc[i + 4];
                        w[i + 6] = hi ? cc[i + 6] : s;
                    }
                }
                pa[qh][0] = (uint4v){w[0], w[1], w[2], w[3]};
                pa[qh][1] = (uint4v){w[4], w[5], w[6], w[7]};
            }

            // PV for this kb's two 16-key slices
            __builtin_amdgcn_s_setprio(1);
            #pragma unroll
            for (int db = 0; db < 2; db++) {
                const int vrow = db * 32 + c;
                #pragma unroll
                for (int tl = 0; tl < 2; tl++) {
                    const int chunk = (kb * 2 + tl) * 2 + hi;
                    short8 vf = *(const short8*)&V_[vrow * 128 + ((chunk ^ (vrow & 7)) * 8)];
                    ctx[0][db] = mfma32u(pa[0][tl], vf, ctx[0][db]);
                    ctx[1][db] = mfma32u(pa[1][tl], vf, ctx[1][db]);
                }
            }
            __builtin_amdgcn_s_setprio(0);
        }

        asm volatile("s_waitcnt vmcnt(0)" ::: "memory");
        __syncthreads();
        cur ^= 1;
    }

    // row sums: partial covers own hi-half t's; partner holds the rest
    #pragma unroll
    for (int qh = 0; qh < 2; qh++) {
        float tot = lsum[qh] + __shfl_xor(lsum[qh], 32);
        if (hi == 0) sums[wid][qh * 32 + c] = tot;
    }
    __syncthreads();
    #pragma unroll
    for (int qh = 0; qh < 2; qh++) {
        #pragma unroll
        for (int rg = 0; rg < 4; rg++) {
            float4 sv = *(const float4*)&sums[wid][qh * 32 + rg * 8 + hi * 4];
            float svf[4] = {sv.x, sv.y, sv.z, sv.w};
            #pragma unroll
            for (int r = 0; r < 4; r++) {
                const float inv = 1.f / svf[r];
                const int reg = rg * 4 + r;
                const int row = q0w + qh * 32 + rg * 8 + hi * 4 + r;
                out[((size_t)b * 2048 + row) * 1024 + h * 64 + c]      = ctx[qh][0][reg] * inv;
                out[((size_t)b * 2048 + row) * 1024 + h * 64 + 32 + c] = ctx[qh][1][reg] * inv;
            }
        }
    }
}

// ---------------- launch ----------------

extern "C" void kernel_launch(void* const* d_in, const int* in_sizes, int n_in,
                              void* d_out, int out_size, void* d_ws, size_t ws_size,
                              hipStream_t stream) {
    const float* X    = (const float*)d_in[0];
    const float* mask = (const float*)d_in[1];
    const float* Wq   = (const float*)d_in[2];
    const float* bq   = (const float*)d_in[3];
    const float* Wk   = (const float*)d_in[4];
    const float* bk   = (const float*)d_in[5];
    const float* Wv   = (const float*)d_in[6];
    const float* bv   = (const float*)d_in[7];
    float* out = (float*)d_out;

    unsigned short* ws  = (unsigned short*)d_ws;
    unsigned short* Xb  = ws;                  // 8192*1024 bf16
    unsigned short* Wqt = Xb + 8388608;        // 1024*1024
    unsigned short* Wkt = Wqt + 1048576;
    unsigned short* Wvt = Wkt + 1048576;
    unsigned short* Qb  = Wvt + 1048576;       // 8192*1024
    unsigned short* Kb  = Qb + 8388608;
    unsigned short* Vtb = Kb + 8388608;        // [1024][8192]

    conv_x<<<2048, 256, 0, stream>>>(X, Xb, 2097152);
    conv_w_t<<<dim3(16, 16, 3), 256, 0, stream>>>(Wq, Wk, Wv, Wqt, Wkt, Wvt);

    gemm_qk<<<dim3(8, 64, 2), 256, 0, stream>>>(Xb, Wqt, Wkt, bq, bk, Qb, Kb);
    gemm_v<<<dim3(64, 8), 256, 0, stream>>>(Wvt, Xb, bv, Vtb);

    attn<<<dim3(64, 8), 256, 0, stream>>>(Qb, Kb, Vtb, mask, out);
}